// Round 4
// baseline (4779.078 us; speedup 1.0000x reference)
//
#include <hip/hip_runtime.h>
#include <stdint.h>

typedef __attribute__((ext_vector_type(4))) float f32x4;
typedef __attribute__((ext_vector_type(8))) short short8;

#define VTH 1.0f
#define T_STEPS 64
#define DDIM 512
#define BM 32            // rows per workgroup
#define LDS_STRIDE 520   // 512 + 8 ushort pad -> conflict-free ds_read_b128

// ws layout (ushort units), 3 MB total
#define OFF_WXH 0
#define OFF_WXM 262144
#define OFF_WXL 524288
#define OFF_WSH 786432
#define OFF_WSM 1048576
#define OFF_WSL 1310720

__device__ __forceinline__ unsigned short f32_to_bf16_rne(float f) {
    uint32_t u = __float_as_uint(f);
    uint32_t r = (u + 0x7FFFu + ((u >> 16) & 1u)) >> 16;
    return (unsigned short)r;
}
__device__ __forceinline__ float bf16_to_f32(unsigned short h) {
    return __uint_as_float(((uint32_t)h) << 16);
}

// 3-term split (exact to ~2^-25): w = H + M + L in bf16, fragment-linear layout.
// F(kb,nt,lane,slot) = ((kb*32+nt)*64 + lane)*8 + slot holds B[k][n] = W[n][k]
// with n = nt*16 + (lane&15), k = kb*32 + (lane>>4)*8 + slot.
__global__ void w_split3_kernel(const float* __restrict__ Wx, const float* __restrict__ Ws,
                                unsigned short* __restrict__ wsb) {
    int tid = blockIdx.x * blockDim.x + threadIdx.x;  // 0 .. 2*512*512-1
    int mat = tid >> 18;
    int rem = tid & 0x3FFFF;
    int n = rem >> 9, k = rem & 511;
    const float* W = mat ? Ws : Wx;
    unsigned short* H = wsb + (mat ? OFF_WSH : OFF_WXH);
    unsigned short* M = wsb + (mat ? OFF_WSM : OFF_WXM);
    unsigned short* L = wsb + (mat ? OFF_WSL : OFF_WXL);
    float w = W[n * DDIM + k];
    unsigned short hb = f32_to_bf16_rne(w);
    float r1 = w - bf16_to_f32(hb);          // exact (Sterbenz)
    unsigned short mb = f32_to_bf16_rne(r1);
    float r2 = r1 - bf16_to_f32(mb);         // exact
    unsigned short lb = f32_to_bf16_rne(r2);
    int kb = k >> 5, g = (k >> 3) & 3, slot = k & 7, nt = n >> 4, c16 = n & 15;
    int F = ((kb * 32 + nt) * 64 + (g * 16 + c16)) * 8 + slot;
    H[F] = hb;
    M[F] = mb;
    L[F] = lb;
}

// One K=512 pass: acc[2][4] (+)= A(32x512 in LDS) @ (W0+W1+W2)(512x64 col-slice).
// NPROD selects how many weight terms are accumulated (A loaded once).
template <int NPROD>
__device__ __forceinline__ void mfma_pass(f32x4 (&acc)[2][4],
                                          const unsigned short* __restrict__ W0,
                                          const unsigned short* __restrict__ W1,
                                          const unsigned short* __restrict__ W2,
                                          const unsigned short* slds,
                                          int wv, int lane) {
    const int g = lane >> 4, r = lane & 15;
    const int arow0 = r * LDS_STRIDE;
    const int arow1 = (16 + r) * LDS_STRIDE;
    short8 Bb[2][NPROD * 4];  // double-buffered B frags: [buf][cf*NPROD + p]
    #pragma unroll
    for (int cf = 0; cf < 4; ++cf) {
        int off = ((wv * 4 + cf) * 64 + lane) * 8;
        Bb[0][cf * NPROD + 0] = *reinterpret_cast<const short8*>(W0 + off);
        if (NPROD > 1) Bb[0][cf * NPROD + 1] = *reinterpret_cast<const short8*>(W1 + off);
        if (NPROD > 2) Bb[0][cf * NPROD + 2] = *reinterpret_cast<const short8*>(W2 + off);
    }
    #pragma unroll
    for (int kb = 0; kb < 16; ++kb) {
        const int cur = kb & 1, nxt = cur ^ 1;
        if (kb < 15) {
            #pragma unroll
            for (int cf = 0; cf < 4; ++cf) {
                int off = (((kb + 1) * 32 + wv * 4 + cf) * 64 + lane) * 8;
                Bb[nxt][cf * NPROD + 0] = *reinterpret_cast<const short8*>(W0 + off);
                if (NPROD > 1) Bb[nxt][cf * NPROD + 1] = *reinterpret_cast<const short8*>(W1 + off);
                if (NPROD > 2) Bb[nxt][cf * NPROD + 2] = *reinterpret_cast<const short8*>(W2 + off);
            }
        }
        const int aoff = kb * 32 + g * 8;
        short8 a0 = *reinterpret_cast<const short8*>(slds + arow0 + aoff);
        short8 a1 = *reinterpret_cast<const short8*>(slds + arow1 + aoff);
        #pragma unroll
        for (int cf = 0; cf < 4; ++cf) {
            #pragma unroll
            for (int p = 0; p < NPROD; ++p) {
                acc[0][cf] = __builtin_amdgcn_mfma_f32_16x16x32_bf16(a0, Bb[cur][cf * NPROD + p], acc[0][cf], 0, 0, 0);
                acc[1][cf] = __builtin_amdgcn_mfma_f32_16x16x32_bf16(a1, Bb[cur][cf * NPROD + p], acc[1][cf], 0, 0, 0);
            }
        }
    }
}

// Persistent per-row-block SNN kernel. 256 WGs x 512 threads; BM=32 rows each.
// u lives in MFMA accumulators; spikes round-trip through LDS (C/D layout -> A layout).
__global__ __launch_bounds__(512, 2) void snn_main_kernel(
    const float* __restrict__ x, const float* __restrict__ bs, const float* __restrict__ bx,
    const unsigned short* __restrict__ wsb, float* __restrict__ out) {
    __shared__ __align__(16) unsigned short slds[BM * LDS_STRIDE];
    const unsigned short* WxH = wsb + OFF_WXH;
    const unsigned short* WxM = wsb + OFF_WXM;
    const unsigned short* WxL = wsb + OFF_WXL;
    const unsigned short* WsH = wsb + OFF_WSH;
    const unsigned short* WsM = wsb + OFF_WSM;
    const unsigned short* WsL = wsb + OFF_WSL;
    const int tid = threadIdx.x;
    const int lane = tid & 63, wv = tid >> 6;
    const int g = lane >> 4, r = lane & 15;
    const int rowbase = blockIdx.x * BM;

    f32x4 acc[2][4];
    #pragma unroll
    for (int rf = 0; rf < 2; ++rf)
        #pragma unroll
        for (int cf = 0; cf < 4; ++cf) acc[rf][cf] = (f32x4){0.f, 0.f, 0.f, 0.f};

    // ---- phase 0: x1 = x @ Wx^T exact-to-fp32 via 3-term x and W splits.
    // Kept products: xh*(H,M,L) + xm*(H,M) + xl*H  (dropped terms <= x*w*2^-24)
    // pass A = xh
    #pragma unroll 4
    for (int it = 0; it < BM; ++it) {
        float v = x[(rowbase + it) * DDIM + tid];
        slds[it * LDS_STRIDE + tid] = f32_to_bf16_rne(v);
    }
    __syncthreads();
    mfma_pass<3>(acc, WxH, WxM, WxL, slds, wv, lane);
    __syncthreads();
    // pass A = xm
    #pragma unroll 4
    for (int it = 0; it < BM; ++it) {
        float v = x[(rowbase + it) * DDIM + tid];
        float h = bf16_to_f32(f32_to_bf16_rne(v));
        slds[it * LDS_STRIDE + tid] = f32_to_bf16_rne(v - h);
    }
    __syncthreads();
    mfma_pass<2>(acc, WxH, WxM, WxL, slds, wv, lane);
    __syncthreads();
    // pass A = xl
    #pragma unroll 4
    for (int it = 0; it < BM; ++it) {
        float v = x[(rowbase + it) * DDIM + tid];
        float h = bf16_to_f32(f32_to_bf16_rne(v));
        float m = bf16_to_f32(f32_to_bf16_rne(v - h));
        slds[it * LDS_STRIDE + tid] = f32_to_bf16_rne(v - h - m);
    }
    __syncthreads();
    mfma_pass<1>(acc, WxH, WxM, WxL, slds, wv, lane);

    // ---- bias add; c = x1 + bs kept in registers ----
    float bxv[4], bsv[4];
    #pragma unroll
    for (int cf = 0; cf < 4; ++cf) {
        int col = wv * 64 + cf * 16 + r;
        bxv[cf] = bx[col];
        bsv[cf] = bs[col];
    }
    f32x4 cR[2][4], aR[2][4];
    #pragma unroll
    for (int rf = 0; rf < 2; ++rf)
        #pragma unroll
        for (int cf = 0; cf < 4; ++cf) {
            #pragma unroll
            for (int i = 0; i < 4; ++i) {
                acc[rf][cf][i] += bxv[cf];
                cR[rf][cf][i] = acc[rf][cf][i] + bsv[cf];
            }
            aR[rf][cf] = (f32x4){0.f, 0.f, 0.f, 0.f};
        }

    // ---- time loop: spike -> (LDS) -> u += s@Ws^T + c ----
    #pragma unroll 1
    for (int t = 0; t < T_STEPS; ++t) {
        __syncthreads();  // previous step's A-fragment reads done before overwrite
        #pragma unroll
        for (int rf = 0; rf < 2; ++rf)
            #pragma unroll
            for (int cf = 0; cf < 4; ++cf)
                #pragma unroll
                for (int i = 0; i < 4; ++i) {
                    float u = acc[rf][cf][i];
                    bool sp = (u >= VTH);
                    float sf = sp ? 1.0f : 0.0f;
                    acc[rf][cf][i] = u - sf;     // soft reset (vth = 1)
                    aR[rf][cf][i] += sf;         // spike count
                    int row = rf * 16 + g * 4 + i;          // C/D: row = (lane>>4)*4 + reg
                    int col = wv * 64 + cf * 16 + r;        // C/D: col = lane&15
                    slds[row * LDS_STRIDE + col] = sp ? (unsigned short)0x3F80 : (unsigned short)0;
                }
        if (t == T_STEPS - 1) break;
        __syncthreads();  // spike writes visible to all waves
        #pragma unroll
        for (int rf = 0; rf < 2; ++rf)
            #pragma unroll
            for (int cf = 0; cf < 4; ++cf)
                #pragma unroll
                for (int i = 0; i < 4; ++i)
                    acc[rf][cf][i] += cR[rf][cf][i];
        mfma_pass<3>(acc, WsH, WsM, WsL, slds, wv, lane);
    }

    // ---- output: a / 64 ----
    #pragma unroll
    for (int rf = 0; rf < 2; ++rf)
        #pragma unroll
        for (int cf = 0; cf < 4; ++cf)
            #pragma unroll
            for (int i = 0; i < 4; ++i) {
                int row = rf * 16 + g * 4 + i;
                int col = wv * 64 + cf * 16 + r;
                out[(rowbase + row) * DDIM + col] = aR[rf][cf][i] * (1.0f / 64.0f);
            }
}

extern "C" void kernel_launch(void* const* d_in, const int* in_sizes, int n_in,
                              void* d_out, int out_size, void* d_ws, size_t ws_size,
                              hipStream_t stream) {
    const float* x  = (const float*)d_in[0];
    const float* Ws = (const float*)d_in[1];
    const float* bs = (const float*)d_in[2];
    const float* Wx = (const float*)d_in[3];
    const float* bx = (const float*)d_in[4];
    float* out = (float*)d_out;

    unsigned short* wsb = (unsigned short*)d_ws;  // 3 MB: 6 x 512KB split matrices

    w_split3_kernel<<<2048, 256, 0, stream>>>(Wx, Ws, wsb);
    snn_main_kernel<<<256, 512, 0, stream>>>(x, bs, bx, wsb, out);
}